// Round 2
// baseline (16910.579 us; speedup 1.0000x reference)
//
#include <hip/hip_runtime.h>
#include <hip/hip_cooperative_groups.h>

// PN_Critic: conv1d(k=1) -> 512-step LSTM -> time-sum -> fc1(relu) -> fc2
// B=256 S=512 D=128 H1=256 H2=512, gates=2048, combined K = 128+512 = 640.
//
// Structure:
//  prep_kernel: Wc[n'][0:128] = (w_ih@conv_w)[n], Wc[n'][128:640] = w_hh[n],
//               bias[n'] = b_ih[n]+b_hh[n]+w_ih[n]@conv_b, with gate-interleaved
//               row order n' = 4*j + g  (n = g*512 + j)  -> cell update is local.
//  lstm_kernel (cooperative, 256 WGs x 256 thr): persistent; B-slice in VGPRs,
//               A-tile staged in LDS per step, c/pooled in registers, h double-
//               buffered in ws, ONE grid.sync per step.
//  fc_kernel:   per-batch-row fused fc1+relu+fc2.

typedef __attribute__((ext_vector_type(8))) short s16x8;
typedef __attribute__((ext_vector_type(4))) float f32x4;

#define B_   256
#define S_   512
#define D_   128
#define H1_  256
#define H2_  512
#define G4_  2048
#define K_   640
#define KP_  648   // padded LDS row (16B-aligned rows, spreads banks)

__device__ __forceinline__ unsigned short f2bf(float f) {
  union { float f; unsigned u; } v; v.f = f;
  unsigned r = v.u + 0x7FFFu + ((v.u >> 16) & 1u);   // round-nearest-even
  return (unsigned short)(r >> 16);
}
__device__ __forceinline__ float sigm(float x) { return 1.f / (1.f + __expf(-x)); }
__device__ __forceinline__ float tanh_(float x) { return 1.f - 2.f / (__expf(2.f * x) + 1.f); }

// ---------------- prep: build combined weight + bias (gate-interleaved rows) --
__global__ void prep_kernel(const float* __restrict__ conv_w, const float* __restrict__ conv_b,
                            const float* __restrict__ w_ih,   const float* __restrict__ b_ih,
                            const float* __restrict__ w_hh,   const float* __restrict__ b_hh,
                            unsigned short* __restrict__ Wc,  float* __restrict__ bias) {
  const int np = blockIdx.x;          // n' = 4*j + g
  const int g = np & 3, j = np >> 2;
  const int n = g * H2_ + j;          // original gate row
  const int tid = threadIdx.x;        // 128 threads

  __shared__ float wrow[H1_];
  __shared__ float red[128];
  wrow[tid]       = w_ih[(size_t)n * H1_ + tid];
  wrow[tid + 128] = w_ih[(size_t)n * H1_ + tid + 128];
  __syncthreads();

  // x-projection part: k = tid (0..127)
  float acc = 0.f;
  for (int h1 = 0; h1 < H1_; ++h1)
    acc += wrow[h1] * conv_w[(size_t)h1 * D_ + tid];
  Wc[(size_t)np * K_ + tid] = f2bf(acc);

  // recurrent part: copy w_hh row (bf16)
  #pragma unroll
  for (int r = 0; r < 4; ++r)
    Wc[(size_t)np * K_ + 128 + tid + r * 128] = f2bf(w_hh[(size_t)n * H2_ + tid + r * 128]);

  // bias[n'] = b_ih + b_hh + w_ih@conv_b
  float p = wrow[tid] * conv_b[tid] + wrow[tid + 128] * conv_b[tid + 128];
  red[tid] = p;
  __syncthreads();
  for (int s = 64; s > 0; s >>= 1) {
    if (tid < s) red[tid] += red[tid + s];
    __syncthreads();
  }
  if (tid == 0) bias[np] = red[0] + b_ih[n] + b_hh[n];
}

// ---------------- persistent cooperative LSTM ------------------------------
__global__ __launch_bounds__(256, 1) void lstm_kernel(
    const float* __restrict__ x, const float* __restrict__ h0,
    const float* __restrict__ c0, const unsigned short* __restrict__ Wc,
    const float* __restrict__ bias, unsigned short* __restrict__ h_bf,
    float* __restrict__ pooled) {
  cooperative_groups::grid_group grid = cooperative_groups::this_grid();

  const int wg = blockIdx.x;       // 256 WGs = 16 mg x 16 ng
  const int mg = wg & 15;          // batch rows mg*16 .. +16
  const int ng = wg >> 4;          // gate cols ng*128 .. +128
  const int tid = threadIdx.x;
  const int wv = tid >> 6;         // wave 0..3: cols wv*32 within the 128
  const int lane = tid & 63;

  __shared__ unsigned short Alds[16][KP_];
  __shared__ float gate_lds[4][16][33];
  __shared__ float bias_lds[128];

  // --- B-slice (32 cols x K=640) into VGPRs, loaded once ---
  const int n0 = ng * 128 + wv * 32;
  s16x8 bfrag0[20], bfrag1[20];
  {
    const int bn0 = n0 + (lane & 15);
    const int bk = (lane >> 4) * 8;
    #pragma unroll
    for (int kk = 0; kk < 20; ++kk) {
      bfrag0[kk] = *(const s16x8*)(Wc + (size_t)bn0 * K_ + kk * 32 + bk);
      bfrag1[kk] = *(const s16x8*)(Wc + (size_t)(bn0 + 16) * K_ + kk * 32 + bk);
    }
  }
  if (tid < 128) bias_lds[tid] = bias[ng * 128 + tid];

  // --- init h buffer 0 from h0 (grid-strided, exact cover) ---
  {
    const int gt = wg * 256 + tid;           // 0..65535
    #pragma unroll
    for (int e = 0; e < 2; ++e) {
      const int idx = gt * 2 + e;            // 0..131071
      h_bf[idx] = f2bf(h0[idx]);
    }
  }

  // --- per-lane cell state: 2 (b,j) pairs owned by this lane forever ---
  int pr[2], pj[2];
  float c_reg[2], pool_acc[2];
  #pragma unroll
  for (int p = 0; p < 2; ++p) {
    const int pi = lane * 2 + p;             // 0..127 within wave
    const int r = pi >> 3, jl = pi & 7;      // 16 rows x 8 j-units
    pr[p] = r; pj[p] = jl;
    const int b = mg * 16 + r;
    const int j = ng * 32 + wv * 8 + jl;
    c_reg[p] = c0[(size_t)b * H2_ + j];
    pool_acc[p] = 0.f;
  }

  grid.sync();

  const int ar = lane & 15;
  const int ak = (lane >> 4) * 8;

  for (int t = 0; t < S_; ++t) {
    const unsigned short* __restrict__ hin = h_bf + (t & 1) * (B_ * H2_);
    unsigned short* __restrict__ hout = h_bf + ((t + 1) & 1) * (B_ * H2_);

    // ---- stage A tile [16 rows][640] : x (fp32->bf16) + h (bf16) ----
    {
      const int r = tid >> 4, ct = tid & 15;
      const int b = mg * 16 + r;
      const float* xp = x + ((size_t)b * S_ + t) * D_ + ct * 8;
      f32x4 v0 = *(const f32x4*)xp;
      f32x4 v1 = *(const f32x4*)(xp + 4);
      s16x8 pk;
      pk[0] = (short)f2bf(v0[0]); pk[1] = (short)f2bf(v0[1]);
      pk[2] = (short)f2bf(v0[2]); pk[3] = (short)f2bf(v0[3]);
      pk[4] = (short)f2bf(v1[0]); pk[5] = (short)f2bf(v1[1]);
      pk[6] = (short)f2bf(v1[2]); pk[7] = (short)f2bf(v1[3]);
      *(s16x8*)&Alds[r][ct * 8] = pk;
      const unsigned short* hrow = hin + (size_t)b * H2_ + ct * 32;
      unsigned short* dst = &Alds[r][128 + ct * 32];
      #pragma unroll
      for (int q = 0; q < 4; ++q)
        *(s16x8*)(dst + q * 8) = *(const s16x8*)(hrow + q * 8);
    }
    __syncthreads();

    // ---- GEMM: wave computes 16 rows x 32 cols, K=640 ----
    f32x4 acc0 = {0.f, 0.f, 0.f, 0.f};
    f32x4 acc1 = {0.f, 0.f, 0.f, 0.f};
    #pragma unroll
    for (int kk = 0; kk < 20; ++kk) {
      s16x8 af = *(const s16x8*)&Alds[ar][kk * 32 + ak];
      acc0 = __builtin_amdgcn_mfma_f32_16x16x32_bf16(af, bfrag0[kk], acc0, 0, 0, 0);
      acc1 = __builtin_amdgcn_mfma_f32_16x16x32_bf16(af, bfrag1[kk], acc1, 0, 0, 0);
    }

    // ---- scatter gates to LDS (C/D layout: col=lane&15, row=(lane>>4)*4+reg) ----
    {
      const int row0 = (lane >> 4) * 4;
      const int dc = lane & 15;
      #pragma unroll
      for (int g = 0; g < 4; ++g) {
        gate_lds[wv][row0 + g][dc]      = acc0[g];
        gate_lds[wv][row0 + g][16 + dc] = acc1[g];
      }
    }
    __syncthreads();

    // ---- cell update: each lane owns 2 (b,j) pairs ----
    #pragma unroll
    for (int p = 0; p < 2; ++p) {
      const int r = pr[p], jl = pj[p];
      const int lc = jl * 4;
      const float gi = gate_lds[wv][r][lc + 0] + bias_lds[wv * 32 + lc + 0];
      const float gf = gate_lds[wv][r][lc + 1] + bias_lds[wv * 32 + lc + 1];
      const float gg = gate_lds[wv][r][lc + 2] + bias_lds[wv * 32 + lc + 2];
      const float go = gate_lds[wv][r][lc + 3] + bias_lds[wv * 32 + lc + 3];
      const float iv = sigm(gi), fv = sigm(gf), gv = tanh_(gg), ov = sigm(go);
      const float cn = fv * c_reg[p] + iv * gv;
      c_reg[p] = cn;
      const float hn = ov * tanh_(cn);
      pool_acc[p] += hn;
      const int b = mg * 16 + r;
      const int j = ng * 32 + wv * 8 + jl;
      hout[(size_t)b * H2_ + j] = f2bf(hn);
    }
    grid.sync();
  }

  #pragma unroll
  for (int p = 0; p < 2; ++p) {
    const int b = mg * 16 + pr[p];
    const int j = ng * 32 + wv * 8 + pj[p];
    pooled[(size_t)b * H2_ + j] = pool_acc[p];
  }
}

// ---------------- fused fc1(relu)+fc2 per batch row -------------------------
__global__ void fc_kernel(const float* __restrict__ pooled,
                          const float* __restrict__ fc1_w, const float* __restrict__ fc1_b,
                          const float* __restrict__ fc2_w, const float* __restrict__ fc2_b,
                          float* __restrict__ out) {
  const int b = blockIdx.x;
  const int tid = threadIdx.x;   // 256
  __shared__ float prow[H2_];
  __shared__ float dec[H2_];
  __shared__ float red[256];
  prow[tid]       = pooled[(size_t)b * H2_ + tid];
  prow[tid + 256] = pooled[(size_t)b * H2_ + tid + 256];
  __syncthreads();
  #pragma unroll
  for (int e = 0; e < 2; ++e) {
    const int o = tid + e * 256;
    const float* wrow = fc1_w + (size_t)o * H2_;
    float a = fc1_b[o];
    #pragma unroll 8
    for (int k = 0; k < H2_; ++k) a += prow[k] * wrow[k];
    dec[o] = fmaxf(a, 0.f);
  }
  __syncthreads();
  red[tid] = dec[tid] * fc2_w[tid] + dec[tid + 256] * fc2_w[tid + 256];
  __syncthreads();
  for (int s = 128; s > 0; s >>= 1) {
    if (tid < s) red[tid] += red[tid + s];
    __syncthreads();
  }
  if (tid == 0) out[b] = red[0] + fc2_b[0];
}

// ---------------- launch -----------------------------------------------------
extern "C" void kernel_launch(void* const* d_in, const int* in_sizes, int n_in,
                              void* d_out, int out_size, void* d_ws, size_t ws_size,
                              hipStream_t stream) {
  const float* x      = (const float*)d_in[0];
  const float* conv_w = (const float*)d_in[1];
  const float* conv_b = (const float*)d_in[2];
  const float* w_ih   = (const float*)d_in[3];
  const float* b_ih   = (const float*)d_in[4];
  const float* w_hh   = (const float*)d_in[5];
  const float* b_hh   = (const float*)d_in[6];
  const float* h0     = (const float*)d_in[7];
  const float* c0     = (const float*)d_in[8];
  const float* fc1_w  = (const float*)d_in[9];
  const float* fc1_b  = (const float*)d_in[10];
  const float* fc2_w  = (const float*)d_in[11];
  const float* fc2_b  = (const float*)d_in[12];
  float* out = (float*)d_out;

  char* ws = (char*)d_ws;
  // ws layout (bytes):
  //   Wc     [2048][640] bf16 : 0        .. 2621440
  //   bias   [2048]      f32  : 2621440  .. 2629632
  //   h_bf [2][256][512] bf16 : 2629632  .. 3153920
  //   pooled [256][512]  f32  : 3153920  .. 3678208
  unsigned short* Wc   = (unsigned short*)(ws);
  float* bias          = (float*)(ws + 2621440);
  unsigned short* h_bf = (unsigned short*)(ws + 2629632);
  float* pooled        = (float*)(ws + 3153920);

  prep_kernel<<<dim3(G4_), dim3(128), 0, stream>>>(conv_w, conv_b, w_ih, b_ih,
                                                   w_hh, b_hh, Wc, bias);

  void* args[7];
  args[0] = (void*)&x;    args[1] = (void*)&h0;   args[2] = (void*)&c0;
  args[3] = (void*)&Wc;   args[4] = (void*)&bias; args[5] = (void*)&h_bf;
  args[6] = (void*)&pooled;
  hipLaunchCooperativeKernel((void*)lstm_kernel, dim3(256), dim3(256), args, 0, stream);

  fc_kernel<<<dim3(B_), dim3(256), 0, stream>>>(pooled, fc1_w, fc1_b, fc2_w, fc2_b, out);
}